// Round 17
// baseline (603.519 us; speedup 1.0000x reference)
//
#include <hip/hip_runtime.h>
#include <cstdint>

// Model dims (fixed): L=128, B=64, DM=1024, H=256, F=512, HID=256, MEM=768,
// N=B*L=8192, NC=6, R=8, NB=30, WIN=10

typedef __attribute__((ext_vector_type(8))) short bf16x8;
typedef __attribute__((ext_vector_type(4))) float f32x4;

__device__ __forceinline__ void gload_lds16(const void* g, void* l) {
  __builtin_amdgcn_global_load_lds(
      (const __attribute__((address_space(1))) void*)g,
      (__attribute__((address_space(3))) void*)l, 16, 0, 0);
}

// ---------------------------------------------------------------------------
// bf16 NT MFMA GEMM (proven): 128x128x32 tile, 4 waves, global_load_lds.
// A row stride lda, C row stride ldc (B row stride == K). Batched via z.
// ---------------------------------------------------------------------------
template<bool HASBIAS, bool ACCUM, bool RELU, bool OUTBF>
__global__ __launch_bounds__(256) void gemm_bf16_nt(
    const ushort* __restrict__ A, const ushort* __restrict__ Bt,
    const float* __restrict__ bias, void* __restrict__ Cv,
    int M, int N, int K, long lda, long ldc,
    long sA, long sB, long sC, long sBias)
{
  const int bz = blockIdx.z;
  A += (long)bz * sA;
  Bt += (long)bz * sB;
  if (HASBIAS) bias += (long)bz * sBias;
  float*  Cf = OUTBF ? nullptr : ((float*)Cv + (long)bz * sC);
  ushort* Cb = OUTBF ? ((ushort*)Cv + (long)bz * sC) : nullptr;

  const int bn = blockIdx.x * 128, bm = blockIdx.y * 128;

  __shared__ ushort As[128][32];
  __shared__ ushort Bs[128][32];

  const int tid = threadIdx.x;
  const int wave = tid >> 6, lane = tid & 63;
  const int wm = (wave >> 1) * 64, wn = (wave & 1) * 64;
  const int fr = lane & 15;
  const int fk = (lane >> 4) * 8;

  f32x4 acc[4][4];
#pragma unroll
  for (int i = 0; i < 4; ++i)
#pragma unroll
    for (int j = 0; j < 4; ++j) acc[i][j] = (f32x4){0.f, 0.f, 0.f, 0.f};

  const int f0 = wave * 2 * 64 + lane;
  const int f1 = f0 + 64;
  const int r0 = f0 >> 2, c0 = (f0 & 3) * 8;
  const int r1 = f1 >> 2, c1 = (f1 & 3) * 8;
  ushort* As0 = (ushort*)As + wave * 2 * 512;
  ushort* As1 = As0 + 512;
  ushort* Bs0 = (ushort*)Bs + wave * 2 * 512;
  ushort* Bs1 = Bs0 + 512;

  for (int k0 = 0; k0 < K; k0 += 32) {
    gload_lds16(A + (long)(bm + r0) * lda + k0 + c0, As0);
    gload_lds16(A + (long)(bm + r1) * lda + k0 + c1, As1);
    gload_lds16(Bt + (long)(bn + r0) * K + k0 + c0, Bs0);
    gload_lds16(Bt + (long)(bn + r1) * K + k0 + c1, Bs1);
    __syncthreads();

    bf16x8 af[4], bfr[4];
#pragma unroll
    for (int f = 0; f < 4; ++f) {
      af[f]  = *(const bf16x8*)&As[wm + f * 16 + fr][fk];
      bfr[f] = *(const bf16x8*)&Bs[wn + f * 16 + fr][fk];
    }
#pragma unroll
    for (int mf = 0; mf < 4; ++mf)
#pragma unroll
      for (int nf = 0; nf < 4; ++nf)
        acc[mf][nf] = __builtin_amdgcn_mfma_f32_16x16x32_bf16(
            af[mf], bfr[nf], acc[mf][nf], 0, 0, 0);
    __syncthreads();
  }

  float bv[4];
#pragma unroll
  for (int nf = 0; nf < 4; ++nf)
    bv[nf] = HASBIAS ? bias[bn + wn + nf * 16 + fr] : 0.f;

  const int crow0 = (lane >> 4) * 4;
#pragma unroll
  for (int mf = 0; mf < 4; ++mf)
#pragma unroll
    for (int r = 0; r < 4; ++r) {
      const long roff = (long)(bm + wm + mf * 16 + crow0 + r) * ldc + bn + wn;
#pragma unroll
      for (int nf = 0; nf < 4; ++nf) {
        float v = acc[mf][nf][r] + bv[nf];
        if (OUTBF) {
          unsigned u = __float_as_uint(v);
          u += 0x7fffu + ((u >> 16) & 1u);
          Cb[roff + nf * 16 + fr] = (ushort)(u >> 16);
        } else {
          if (ACCUM) v += Cf[roff + nf * 16 + fr];
          if (RELU) v = fmaxf(v, 0.f);
          Cf[roff + nf * 16 + fr] = v;
        }
      }
    }
}

// ---------------------------------------------------------------------------
// helpers
// ---------------------------------------------------------------------------
__device__ __forceinline__ unsigned short f2bf(float f) {
  unsigned u = __float_as_uint(f);
  u += 0x7fffu + ((u >> 16) & 1u);
  return (unsigned short)(u >> 16);
}
__device__ __forceinline__ float bf2f(ushort v) {
  return __uint_as_float(((unsigned)v) << 16);
}
__device__ __forceinline__ float fast_sig(float x) {
  return __builtin_amdgcn_rcpf(1.f + __expf(-x));
}
__device__ __forceinline__ float fast_tanh(float x) {
  return 2.f * fast_sig(2.f * x) - 1.f;
}

__device__ __forceinline__ int sdot4_(uint a, uint b, int c) {
#if __has_builtin(__builtin_amdgcn_sdot4)
  return __builtin_amdgcn_sdot4((int)a, (int)b, c, false);
#else
  int r = c;
  r += ((int)(a << 24) >> 24) * ((int)(b << 24) >> 24);
  r += ((int)(a << 16) >> 24) * ((int)(b << 16) >> 24);
  r += ((int)(a << 8)  >> 24) * ((int)(b << 8)  >> 24);
  r += ((int)a >> 24)         * ((int)b >> 24);
  return r;
#endif
}

// ---------------------------------------------------------------------------
// prep1: Whh int8 pack (bids 0..1023) + W_rel basis combination (1024..1535)
// ---------------------------------------------------------------------------
__global__ __launch_bounds__(256) void prep1_k(
    const float* __restrict__ Whh0, const float* __restrict__ Whh1,
    uint* __restrict__ Wq, float* __restrict__ fscale,
    const float* __restrict__ basis, const float* __restrict__ comp,
    ushort* __restrict__ wrel2t)
{
  __shared__ float cs[240];
  const int bid = blockIdx.x;
  if (bid < 1024) {
    const int wid = (bid * 256 + threadIdx.x) >> 6;
    const int lane = threadIdx.x & 63;
    const int l = wid >> 11;
    const int wid2 = wid & 2047;
    const int d = wid2 >> 10, gi = wid2 & 1023;
    const float* Whh = l ? Whh1 : Whh0;
    const float* row = Whh + ((long)d * 1024 + gi) * 256 + lane * 4;
    float v0 = row[0], v1 = row[1], v2 = row[2], v3 = row[3];
    float am = fmaxf(fmaxf(fabsf(v0), fabsf(v1)), fmaxf(fabsf(v2), fabsf(v3)));
#pragma unroll
    for (int off = 32; off > 0; off >>= 1) am = fmaxf(am, __shfl_xor(am, off, 64));
    am = fmaxf(am, 1e-12f);
    const float inv = 127.f / am;
    int q0 = __float2int_rn(v0 * inv), q1 = __float2int_rn(v1 * inv);
    int q2 = __float2int_rn(v2 * inv), q3 = __float2int_rn(v3 * inv);
    uint w = (uint)(q0 & 255) | ((uint)(q1 & 255) << 8) |
             ((uint)(q2 & 255) << 16) | ((uint)(q3 & 255) << 24);
    Wq[(long)l * 131072 + ((long)d * 64 + lane) * 1024 + gi] = w;
    if (lane == 0) fscale[l * 2048 + d * 1024 + gi] = am / 127.f;
    return;
  }
  // wrel: f = bid - 1024 (0..511)
  const int f = bid - 1024;
  const int o = threadIdx.x;
  if (o < 240) cs[o] = comp[o];
  __syncthreads();
  float acc[8];
#pragma unroll
  for (int r = 0; r < 8; ++r) acc[r] = 0.f;
  for (int bb = 0; bb < 30; ++bb) {
    const float v = basis[((long)bb * 512 + f) * 256 + o];
#pragma unroll
    for (int r = 0; r < 8; ++r) acc[r] = fmaf(cs[r * 30 + bb], v, acc[r]);
  }
#pragma unroll
  for (int r = 0; r < 8; ++r)
    wrel2t[((long)(r * 256 + o)) * 512 + f] = f2bf(acc[r]);
}

// ---------------------------------------------------------------------------
// prep2: f32->bf16 cvt (U/Wih0/Wih1, bids 0..11263), stacked bias (11264/5),
// transpose jobs (11266..12353).
// ---------------------------------------------------------------------------
__global__ __launch_bounds__(256) void prep2_k(
    const float* __restrict__ U, ushort* __restrict__ ubf,
    const float* __restrict__ W0, ushort* __restrict__ w0,
    const float* __restrict__ W1, ushort* __restrict__ w1,
    const float* __restrict__ b_rgcn, float* __restrict__ biasSW,
    const float* __restrict__ s0, ushort* __restrict__ d0,   // W_root
    const float* __restrict__ s1, const float* __restrict__ s2,
    ushort* __restrict__ d12,                                // gc stacked
    const float* __restrict__ s3, ushort* __restrict__ d3,   // Wm
    const float* __restrict__ s4, ushort* __restrict__ d4,   // Wl
    const float* __restrict__ s5, ushort* __restrict__ d5)   // W_scalar
{
  __shared__ float tile[32][33];
  const int bid0 = blockIdx.x;
  if (bid0 < 11264) {
    const float* src; ushort* dst; long base;
    if (bid0 < 8192)       { src = U;  dst = ubf; base = (long)bid0 * 1024; }
    else if (bid0 < 10240) { src = W0; dst = w0;  base = (long)(bid0 - 8192) * 1024; }
    else                   { src = W1; dst = w1;  base = (long)(bid0 - 10240) * 1024; }
    const long i = base + threadIdx.x * 4;
    float4 v = *(const float4*)(src + i);
    ushort4 o;
    o.x = f2bf(v.x); o.y = f2bf(v.y); o.z = f2bf(v.z); o.w = f2bf(v.w);
    *(ushort4*)(dst + i) = o;
    return;
  }
  if (bid0 < 11266) {
    const int idx = (bid0 - 11264) * 256 + threadIdx.x;
    if (idx < 384) biasSW[idx] = (idx < 128) ? 0.f : b_rgcn[idx - 128];
    return;
  }
  const int bid = bid0 - 11266;  // 0..1087
  const float* src; ushort* dst; int C, gx, local, dstStride, dstOff;
  if (bid < 128)       { src = s0; dst = d0;  C = 256; gx = 8;  local = bid;        dstStride = 512; dstOff = 0; }
  else if (bid < 192)  { src = s1; dst = d12; C = 256; gx = 8;  local = bid - 128;  dstStride = 512; dstOff = 0; }
  else if (bid < 256)  { src = s2; dst = d12; C = 256; gx = 8;  local = bid - 192;  dstStride = 512; dstOff = 256; }
  else if (bid < 832)  { src = s3; dst = d3;  C = 768; gx = 24; local = bid - 256;  dstStride = 768; dstOff = 0; }
  else if (bid < 1024) { src = s4; dst = d4;  C = 256; gx = 8;  local = bid - 832;  dstStride = 768; dstOff = 0; }
  else                 { src = s5; dst = d5;  C = 128; gx = 4;  local = bid - 1024; dstStride = 512; dstOff = 0; }
  const int c0 = (local % gx) * 32, r0 = (local / gx) * 32;
  const int tx = threadIdx.x & 31, ty = threadIdx.x >> 5;
#pragma unroll
  for (int j = 0; j < 4; ++j)
    tile[ty + j * 8][tx] = src[(long)(r0 + ty + j * 8) * C + c0 + tx];
  __syncthreads();
#pragma unroll
  for (int j = 0; j < 4; ++j)
    dst[(long)(c0 + ty + j * 8) * dstStride + dstOff + r0 + tx] = f2bf(tile[tx][ty + j * 8]);
}

// ---------------------------------------------------------------------------
// LSTM v4 (proven; bf16 gates): int8 weights streamed from L2, int8 h via
// LDS broadcast, sdot4; bf16 output with row stride ldo.
// ---------------------------------------------------------------------------
__global__ __launch_bounds__(1024) void lstm4_k(
    const ushort* __restrict__ Xg,
    const uint* __restrict__ Wq,
    const float* __restrict__ fscale,
    ushort* __restrict__ out,
    int bmajor, long ldo)
{
  const int bx = blockIdx.x;
  const int d = bx >> 6, b = bx & 63;
  const int tid = threadIdx.x;

  __shared__ uint hq[2][64];
  __shared__ float preactF[1024];

  uint w[64];
  const uint* wrow = Wq + (long)d * 65536 + tid;
#pragma unroll
  for (int k4 = 0; k4 < 64; ++k4) w[k4] = wrow[k4 * 1024];

  if (tid < 128) ((uint*)hq)[tid] = 0u;

  const float fsc = fscale[d * 1024 + tid] * (1.0f / 127.0f);
  const ushort* Xd = Xg + (long)d * 8192 * 1024;

  float c = 0.f;
  float x0 = 0.f, x1 = 0.f, x2 = 0.f, x3 = 0.f;
  if (tid < 256) {
    const ushort* xr = Xd + ((long)((d ? 127 : 0) * 64 + b)) * 1024;
    x0 = bf2f(xr[tid]); x1 = bf2f(xr[tid + 256]);
    x2 = bf2f(xr[tid + 512]); x3 = bf2f(xr[tid + 768]);
  }
  __syncthreads();

  int cur = 0;
  for (int step = 0; step < 128; ++step) {
    const int t = d ? 127 - step : step;

    float n0 = 0.f, n1 = 0.f, n2 = 0.f, n3 = 0.f;
    if (tid < 256 && step + 1 < 128) {
      const ushort* xr = Xd + ((long)((d ? 126 - step : step + 1) * 64 + b)) * 1024;
      n0 = bf2f(xr[tid]); n1 = bf2f(xr[tid + 256]);
      n2 = bf2f(xr[tid + 512]); n3 = bf2f(xr[tid + 768]);
    }

    int acc = 0;
    const uint4* hrow = (const uint4*)hq[cur];
#pragma unroll
    for (int k16 = 0; k16 < 16; ++k16) {
      uint4 h4 = hrow[k16];
      acc = sdot4_(w[k16 * 4 + 0], h4.x, acc);
      acc = sdot4_(w[k16 * 4 + 1], h4.y, acc);
      acc = sdot4_(w[k16 * 4 + 2], h4.z, acc);
      acc = sdot4_(w[k16 * 4 + 3], h4.w, acc);
    }
    preactF[tid] = (float)acc * fsc;
    __syncthreads();

    if (tid < 256) {
      float p0 = x0 + preactF[tid];
      float p1 = x1 + preactF[tid + 256];
      float p2 = x2 + preactF[tid + 512];
      float p3 = x3 + preactF[tid + 768];
      const float ig = fast_sig(p0), fg = fast_sig(p1);
      const float gg = fast_tanh(p2), og = fast_sig(p3);
      c = fg * c + ig * gg;
      const float h = og * fast_tanh(c);
      const long row = bmajor ? ((long)b * 128 + t) : ((long)t * 64 + b);
      out[row * ldo + (d << 8) + tid] = f2bf(h);
      ((char*)hq[cur ^ 1])[tid] = (char)__float2int_rn(h * 127.f);
      x0 = n0; x1 = n1; x2 = n2; x3 = n3;
    }
    __syncthreads();
    cur ^= 1;
  }
}

// ---------------------------------------------------------------------------
// RGCN gather FUSED with edge-attention softmax (proven). scaleM [8192][384]:
// cols [0:128) = scale, cols [128:384) = hroot.
// ---------------------------------------------------------------------------
__global__ __launch_bounds__(256) void rgcn_fused_k(
    const float* __restrict__ scaleM, const ushort* __restrict__ xrel,
    const int* __restrict__ spk, ushort* __restrict__ hagg)
{
  const int n = blockIdx.x;
  const int b = n >> 7, t = n & 127;
  const int o = threadIdx.x;
  const int lo = max(t - 10, 0), hi = min(t + 10, 127);
  const int cnt = hi - lo + 1;

  __shared__ float sc[128], red[128];
  __shared__ int spks[21];
  __shared__ int spkt_s;

  if (o < 128) {
    const float v = scaleM[((long)(b * 128 + o)) * 384 + t];
    sc[o] = v; red[o] = v;
  }
  if (o == 0) spkt_s = spk[t * 64 + b];
  if (o >= 128 && o - 128 < cnt) spks[o - 128] = spk[(lo + o - 128) * 64 + b];
  __syncthreads();
  for (int off = 64; off > 0; off >>= 1) {
    if (o < off) red[o] = fmaxf(red[o], red[o + off]);
    __syncthreads();
  }
  const float m = red[0];
  __syncthreads();
  if (o < 128) {
    const float e = expf(sc[o] - m);
    sc[o] = e;
    const int dd = o - t;
    const bool inwin = (dd <= 10) && (dd >= -10);
    red[o] = e * (inwin ? 1.0f : 1e-10f);
  }
  __syncthreads();
  for (int off = 64; off > 0; off >>= 1) {
    if (o < off) red[o] += red[o + off];
    __syncthreads();
  }
  const float inv_msum = 1.0f / red[0];
  __syncthreads();

  const int spkt = spkt_s;
  float acc = scaleM[(long)n * 384 + 128 + o];
  for (int q = 0; q < cnt; ++q) {
    const int s = lo + q;
    const float wv = sc[s] * inv_msum;
    const int et = spkt * 4 + spks[q] * 2 + ((t < s) ? 0 : 1);
    acc = fmaf(bf2f(xrel[(((long)(b * 128 + s)) * 8 + et) * 256 + o]), wv, acc);
  }
  hagg[(long)n * 512 + o] = f2bf(acc);
}

// GraphConv neighbor aggregation: reads h half, writes agg half (cols 256+)
__global__ __launch_bounds__(256) void agg_k(ushort* __restrict__ hagg) {
  const int n = blockIdx.x;
  const int b = n >> 7, t = n & 127;
  const int o = threadIdx.x;
  const int lo = max(t - 10, 0), hi = min(t + 10, 127);
  float acc = 0.f;
  for (int s = lo; s <= hi; ++s) acc += bf2f(hagg[((long)(b * 128 + s)) * 512 + o]);
  hagg[(long)n * 512 + 256 + o] = f2bf(acc);
}

// Batched ushort transpose: dst[b](C x R) = src[b](R x C)^T, R=128, C=768.
__global__ __launch_bounds__(256) void emt_k(const ushort* __restrict__ src,
                                             ushort* __restrict__ dst) {
  __shared__ ushort tile[32][33];
  const int c0 = blockIdx.x * 32;
  const int r0 = blockIdx.y * 32;
  const int b = blockIdx.z;
  const ushort* s = src + (long)b * 98304;
  ushort* d = dst + (long)b * 98304;
  const int tx = threadIdx.x & 31, ty = threadIdx.x >> 5;
#pragma unroll
  for (int j = 0; j < 4; ++j)
    tile[ty + j * 8][tx] = s[(long)(r0 + ty + j * 8) * 768 + c0 + tx];
  __syncthreads();
#pragma unroll
  for (int j = 0; j < 4; ++j)
    d[(long)(c0 + ty + j * 8) * 128 + r0 + tx] = tile[tx][ty + j * 8];
}

// ---------------------------------------------------------------------------
// MEGA attention: one block per batch b. Phase 1: logits = xtr @ em^T (K=768)
// into transposed f32 LDS tile. Phase 2: in-LDS softmax
// a_s = e_s*um_s / sum(e*um) (algebraically identical to ref chain).
// Phase 3: att = a @ em (A from LDS, B = emT) -> bf16 attbf.
// ---------------------------------------------------------------------------
__global__ __launch_bounds__(256) void mega_attn_k(
    const ushort* __restrict__ xtr,   // [8192][768] bf16 (b-major)
    const ushort* __restrict__ em,    // [8192][768] bf16 (xemb)
    const ushort* __restrict__ emT,   // [64][768][128] bf16
    const float* __restrict__ umask,  // [64][128]
    ushort* __restrict__ att)         // [8192][768] bf16
{
  const int b = blockIdx.x;
  const ushort* A = xtr + (long)b * 98304;
  const ushort* B = em + (long)b * 98304;
  const ushort* BT = emT + (long)b * 98304;
  ushort* C = att + (long)b * 98304;

  __shared__ ushort As[128][32];
  __shared__ ushort Bs[128][32];
  __shared__ float logT[128][129];   // logits transposed [s][t]
  __shared__ ushort albf[128][136];  // a bf16 [t][s]
  __shared__ float um_l[128];
  __shared__ float red2[2][128];

  const int tid = threadIdx.x;
  const int wave = tid >> 6, lane = tid & 63;
  const int wm = (wave >> 1) * 64, wn = (wave & 1) * 64;
  const int fr = lane & 15;
  const int fk = (lane >> 4) * 8;
  const int crow0 = (lane >> 4) * 4;

  if (tid < 128) um_l[tid] = umask[b * 128 + tid];

  const int f0 = wave * 2 * 64 + lane;
  const int f1 = f0 + 64;
  const int r0 = f0 >> 2, c0 = (f0 & 3) * 8;
  const int r1 = f1 >> 2, c1 = (f1 & 3) * 8;
  ushort* As0 = (ushort*)As + wave * 2 * 512;
  ushort* As1 = As0 + 512;
  ushort* Bs0 = (ushort*)Bs + wave * 2 * 512;
  ushort* Bs1 = Bs0 + 512;

  // --- phase 1: logits ---
  f32x4 acc[4][4];
#pragma unroll
  for (int i = 0; i < 4; ++i)
#pragma unroll
    for (int j = 0; j < 4; ++j) acc[i][j] = (f32x4){0.f, 0.f, 0.f, 0.f};

  for (int k0 = 0; k0 < 768; k0 += 32) {
    gload_lds16(A + (long)r0 * 768 + k0 + c0, As0);
    gload_lds16(A + (long)r1 * 768 + k0 + c1, As1);
    gload_lds16(B + (long)r0 * 768 + k0 + c0, Bs0);
    gload_lds16(B + (long)r1 * 768 + k0 + c1, Bs1);
    __syncthreads();
    bf16x8 af[4], bfr[4];
#pragma unroll
    for (int f = 0; f < 4; ++f) {
      af[f]  = *(const bf16x8*)&As[wm + f * 16 + fr][fk];
      bfr[f] = *(const bf16x8*)&Bs[wn + f * 16 + fr][fk];
    }
#pragma unroll
    for (int mf = 0; mf < 4; ++mf)
#pragma unroll
      for (int nf = 0; nf < 4; ++nf)
        acc[mf][nf] = __builtin_amdgcn_mfma_f32_16x16x32_bf16(
            af[mf], bfr[nf], acc[mf][nf], 0, 0, 0);
    __syncthreads();
  }
#pragma unroll
  for (int mf = 0; mf < 4; ++mf)
#pragma unroll
    for (int r = 0; r < 4; ++r)
#pragma unroll
      for (int nf = 0; nf < 4; ++nf)
        logT[wn + nf * 16 + fr][wm + mf * 16 + crow0 + r] = acc[mf][nf][r];
  __syncthreads();

  // --- phase 2: softmax (2 threads per row t; halves of s) ---
  {
    const int t = tid & 127, hh = tid >> 7;
    float vmax = -1e30f;
    for (int s = hh * 64; s < hh * 64 + 64; ++s) {
      const float um = um_l[s];
      vmax = fmaxf(vmax, tanhf(logT[s][t] * um * um));
    }
    red2[hh][t] = vmax;
    __syncthreads();
    const float m = fmaxf(red2[0][t], red2[1][t]);
    __syncthreads();
    float lsum = 0.f;
    for (int s = hh * 64; s < hh * 64 + 64; ++s) {
      const float um = um_l[s];
      lsum += expf(tanhf(logT[s][t] * um * um) - m) * um;
    }
    red2[hh][t] = lsum;
    __syncthreads();
    const float invS = 1.f / (red2[0][t] + red2[1][t]);
    for (int s = hh * 64; s < hh * 64 + 64; ++s) {
      const float um = um_l[s];
      albf[t][s] = f2bf(expf(tanhf(logT[s][t] * um * um) - m) * um * invS);
    }
  }
  __syncthreads();

  // --- phase 3: att = a @ em (Bt = emT), 6 N-tiles x K=128 ---
  for (int nt = 0; nt < 6; ++nt) {
    f32x4 acc2[4][4];
#pragma unroll
    for (int i = 0; i < 4; ++i)
#pragma unroll
      for (int j = 0; j < 4; ++j) acc2[i][j] = (f32x4){0.f, 0.f, 0.f, 0.f};
    for (int k0 = 0; k0 < 128; k0 += 32) {
      gload_lds16(BT + (long)(nt * 128 + r0) * 128 + k0 + c0, Bs0);
      gload_lds16(BT + (long)(nt * 128 + r1) * 128 + k0 + c1, Bs1);
      __syncthreads();
      bf16x8 af[4], bfr[4];
#pragma unroll
      for (int f = 0; f < 4; ++f) {
        af[f]  = *(const bf16x8*)&albf[wm + f * 16 + fr][k0 + fk];
        bfr[f] = *(const bf16x8*)&Bs[wn + f * 16 + fr][fk];
      }
#pragma unroll
      for (int mf = 0; mf < 4; ++mf)
#pragma unroll
        for (int nf = 0; nf < 4; ++nf)
          acc2[mf][nf] = __builtin_amdgcn_mfma_f32_16x16x32_bf16(
              af[mf], bfr[nf], acc2[mf][nf], 0, 0, 0);
      __syncthreads();
    }
#pragma unroll
    for (int mf = 0; mf < 4; ++mf)
#pragma unroll
      for (int r = 0; r < 4; ++r) {
        const long roff = (long)(wm + mf * 16 + crow0 + r) * 768 + nt * 128 + wn;
#pragma unroll
        for (int nf = 0; nf < 4; ++nf)
          C[roff + nf * 16 + fr] = f2bf(acc2[mf][nf][r]);
      }
  }
}

__global__ __launch_bounds__(256) void final_k(const float* __restrict__ hidden,
                                               const float* __restrict__ Ws,
                                               const float* __restrict__ bs,
                                               float* __restrict__ out) {
  __shared__ float wsl[256 * 6];
  const int tid = threadIdx.x;
#pragma unroll
  for (int j = 0; j < 6; ++j) wsl[tid * 6 + j] = Ws[tid * 6 + j];
  __syncthreads();
  const int wave = tid >> 6, lane = tid & 63;
  const int n = blockIdx.x * 4 + wave;
  const float4 hv = *(const float4*)&hidden[(long)n * 256 + lane * 4];
  const float hvv[4] = {hv.x, hv.y, hv.z, hv.w};
  float a[6];
#pragma unroll
  for (int c = 0; c < 6; ++c) a[c] = 0.f;
#pragma unroll
  for (int j = 0; j < 4; ++j)
#pragma unroll
    for (int c = 0; c < 6; ++c)
      a[c] = fmaf(hvv[j], wsl[(lane * 4 + j) * 6 + c], a[c]);
#pragma unroll
  for (int off = 32; off > 0; off >>= 1)
#pragma unroll
    for (int c = 0; c < 6; ++c)
      a[c] += __shfl_xor(a[c], off, 64);
  if (lane == 0) {
    float v[6], m = -1e30f;
#pragma unroll
    for (int c = 0; c < 6; ++c) { v[c] = a[c] + bs[c]; m = fmaxf(m, v[c]); }
    float sum = 0.f;
#pragma unroll
    for (int c = 0; c < 6; ++c) sum += expf(v[c] - m);
    const float lse = m + logf(sum);
#pragma unroll
    for (int c = 0; c < 6; ++c) out[(long)n * 6 + c] = v[c] - lse;
  }
}

// ---------------------------------------------------------------------------
// Orchestration
// ---------------------------------------------------------------------------
extern "C" void kernel_launch(void* const* d_in, const int* in_sizes, int n_in,
                              void* d_out, int out_size, void* d_ws, size_t ws_size,
                              hipStream_t stream) {
  const float* U        = (const float*)d_in[0];
  const float* umask    = (const float*)d_in[1];
  const float* Wih0     = (const float*)d_in[2];
  const float* Whh0     = (const float*)d_in[3];
  const float* b0       = (const float*)d_in[4];
  const float* Wih1     = (const float*)d_in[5];
  const float* Whh1     = (const float*)d_in[6];
  const float* b1       = (const float*)d_in[7];
  const float* W_scalar = (const float*)d_in[8];
  const float* basis    = (const float*)d_in[9];
  const float* comp     = (const float*)d_in[10];
  const float* W_root   = (const float*)d_in[11];
  const float* b_rgcn   = (const float*)d_in[12];
  const float* gc_W1    = (const float*)d_in[13];
  const float* gc_W2    = (const float*)d_in[14];
  const float* gc_b     = (const float*)d_in[15];
  const float* Wm       = (const float*)d_in[16];
  const float* bm       = (const float*)d_in[17];
  const float* Wl       = (const float*)d_in[18];
  const float* bl       = (const float*)d_in[19];
  const float* Wsw      = (const float*)d_in[20];
  const float* bsw      = (const float*)d_in[21];
  const int*   speakers = (const int*)d_in[22];

  float* ws = (float*)d_ws;
  float* gates   = ws + 0L;          // 16.78M f: gatesbf | scaleM -> xrelbf -> xtrbf
  float* feats   = ws + 16777216L;   //  4.19M f: wih0bf/wih1bf -> attbf
  float* xbuf    = ws + 20971520L;   //  4.19M f: ubf -> hagg -> emT
  float* feats0  = ws + 25165824L;   //  4.19M f: f0bf -> xemb [8192][768]
  float* scaleb  = ws + 29360128L;   //  2.10M f with scoresb: hidden
  float* scoresb = ws + 30408704L;
  float* wrelr   = ws + 31457280L;   //  1.05M f: wrel2t bf16
  uint*  wq      = (uint*)(ws + 34603008L);   // 262,144 dwords
  float* fsc     = ws + 34865152L;            // 4,096
  float* wTr     = ws + 34869248L;            // 557,056 f (transposed weights)
  float* biasSW  = ws + 35426304L;            // 384 f

  ushort* ubf    = (ushort*)xbuf;
  ushort* wih0bf = (ushort*)feats;
  ushort* wih1bf = (ushort*)(feats + 1048576L);
  ushort* f0bf   = (ushort*)feats0;
  ushort* xemb   = (ushort*)feats0;              // [8192][768]
  ushort* wrel2t = (ushort*)wrelr;
  ushort* wswr   = (ushort*)wTr;                 // 384x512 stacked
  ushort* gcW12t = wswr + 196608L;               // 256x512 stacked
  ushort* Wmt    = gcW12t + 131072L;             // 768x768
  ushort* Wlt    = Wmt + 589824L;                // 256x768

  ushort* gatesbf = (ushort*)gates;
  float*  scaleM  = gates + 8388608L;            // [8192][384]
  ushort* hagg    = (ushort*)xbuf;               // [8192][512]
  ushort* emT     = (ushort*)xbuf;               // [64][768][128]
  ushort* xrelbf  = (ushort*)gates;
  ushort* xtrbf   = (ushort*)gates;
  ushort* attbf   = (ushort*)feats;

  float*  hiddenb = scaleb;

  // --- weight prep (2 dispatches) ---
  prep1_k<<<1536, 256, 0, stream>>>(Whh0, Whh1, wq, fsc, basis, comp, wrel2t);
  prep2_k<<<12354, 256, 0, stream>>>(U, ubf, Wih0, wih0bf, Wih1, wih1bf,
                                     b_rgcn, biasSW,
                                     W_root, wswr + 65536L, gc_W1, gc_W2, gcW12t,
                                     Wm, Wmt, Wl, Wlt, W_scalar, wswr);

  // --- layer 0 ---
  gemm_bf16_nt<true, false, false, true><<<dim3(8, 64, 2), 256, 0, stream>>>(
      ubf, wih0bf, b0, gatesbf, 8192, 1024, 1024, 1024L, 1024L,
      0L, 1048576L, 8388608L, 1024L);
  lstm4_k<<<128, 1024, 0, stream>>>(gatesbf, wq, fsc, f0bf, 0, 512L);

  // --- layer 1 ---
  gemm_bf16_nt<true, false, false, true><<<dim3(8, 64, 2), 256, 0, stream>>>(
      f0bf, wih1bf, b1, gatesbf, 8192, 1024, 512, 512L, 1024L,
      0L, 524288L, 8388608L, 1024L);
  lstm4_k<<<128, 1024, 0, stream>>>(gatesbf, wq + 131072, fsc + 2048, xemb, 1, 768L);

  // --- merged edge-scale | W_root GEMM + xrel + fused RGCN ---
  gemm_bf16_nt<true, false, false, false><<<dim3(3, 64, 1), 256, 0, stream>>>(
      xemb, wswr, biasSW, scaleM, 8192, 384, 512, 768L, 384L, 0L, 0L, 0L, 0L);
  gemm_bf16_nt<false, false, false, true><<<dim3(16, 64, 1), 256, 0, stream>>>(
      xemb, wrel2t, nullptr, xrelbf, 8192, 2048, 512, 768L, 2048L, 0L, 0L, 0L, 0L);
  rgcn_fused_k<<<8192, 256, 0, stream>>>(scaleM, xrelbf, speakers, hagg);

  // --- GraphConv ---
  agg_k<<<8192, 256, 0, stream>>>(hagg);
  gemm_bf16_nt<true, false, false, true><<<dim3(2, 64, 1), 256, 0, stream>>>(
      hagg, gcW12t, gc_b, xemb + 512, 8192, 256, 512, 512L, 768L, 0L, 0L, 0L, 0L);

  // --- matching attention ---
  gemm_bf16_nt<true, false, false, true><<<dim3(6, 64, 1), 256, 0, stream>>>(
      xemb, Wmt, bm, xtrbf, 8192, 768, 768, 768L, 768L, 0L, 0L, 0L, 0L);
  emt_k<<<dim3(24, 4, 64), 256, 0, stream>>>(xemb, emT);
  mega_attn_k<<<64, 256, 0, stream>>>(xtrbf, xemb, emT, umask, attbf);

  // --- classifier ---
  gemm_bf16_nt<true, false, true, false><<<dim3(2, 64, 1), 256, 0, stream>>>(
      attbf, Wlt, bl, hiddenb, 8192, 256, 768, 768L, 256L, 0L, 0L, 0L, 0L);
  final_k<<<2048, 256, 0, stream>>>(hiddenb, Wsw, bsw, (float*)d_out);
}

// Round 18
// 579.429 us; speedup vs baseline: 1.0416x; 1.0416x over previous
//
#include <hip/hip_runtime.h>
#include <cstdint>

// Model dims (fixed): L=128, B=64, DM=1024, H=256, F=512, HID=256, MEM=768,
// N=B*L=8192, NC=6, R=8, NB=30, WIN=10

typedef __attribute__((ext_vector_type(8))) short bf16x8;
typedef __attribute__((ext_vector_type(4))) float f32x4;

__device__ __forceinline__ void gload_lds16(const void* g, void* l) {
  __builtin_amdgcn_global_load_lds(
      (const __attribute__((address_space(1))) void*)g,
      (__attribute__((address_space(3))) void*)l, 16, 0, 0);
}

// ---------------------------------------------------------------------------
// bf16 NT MFMA GEMM (proven): 128x128x32 tile, 4 waves, global_load_lds.
// A row stride lda, C row stride ldc (B row stride == K). Batched via z.
// ---------------------------------------------------------------------------
template<bool HASBIAS, bool ACCUM, bool RELU, bool OUTBF>
__global__ __launch_bounds__(256) void gemm_bf16_nt(
    const ushort* __restrict__ A, const ushort* __restrict__ Bt,
    const float* __restrict__ bias, void* __restrict__ Cv,
    int M, int N, int K, long lda, long ldc,
    long sA, long sB, long sC, long sBias)
{
  const int bz = blockIdx.z;
  A += (long)bz * sA;
  Bt += (long)bz * sB;
  if (HASBIAS) bias += (long)bz * sBias;
  float*  Cf = OUTBF ? nullptr : ((float*)Cv + (long)bz * sC);
  ushort* Cb = OUTBF ? ((ushort*)Cv + (long)bz * sC) : nullptr;

  const int bn = blockIdx.x * 128, bm = blockIdx.y * 128;

  __shared__ ushort As[128][32];
  __shared__ ushort Bs[128][32];

  const int tid = threadIdx.x;
  const int wave = tid >> 6, lane = tid & 63;
  const int wm = (wave >> 1) * 64, wn = (wave & 1) * 64;
  const int fr = lane & 15;
  const int fk = (lane >> 4) * 8;

  f32x4 acc[4][4];
#pragma unroll
  for (int i = 0; i < 4; ++i)
#pragma unroll
    for (int j = 0; j < 4; ++j) acc[i][j] = (f32x4){0.f, 0.f, 0.f, 0.f};

  const int f0 = wave * 2 * 64 + lane;
  const int f1 = f0 + 64;
  const int r0 = f0 >> 2, c0 = (f0 & 3) * 8;
  const int r1 = f1 >> 2, c1 = (f1 & 3) * 8;
  ushort* As0 = (ushort*)As + wave * 2 * 512;
  ushort* As1 = As0 + 512;
  ushort* Bs0 = (ushort*)Bs + wave * 2 * 512;
  ushort* Bs1 = Bs0 + 512;

  for (int k0 = 0; k0 < K; k0 += 32) {
    gload_lds16(A + (long)(bm + r0) * lda + k0 + c0, As0);
    gload_lds16(A + (long)(bm + r1) * lda + k0 + c1, As1);
    gload_lds16(Bt + (long)(bn + r0) * K + k0 + c0, Bs0);
    gload_lds16(Bt + (long)(bn + r1) * K + k0 + c1, Bs1);
    __syncthreads();

    bf16x8 af[4], bfr[4];
#pragma unroll
    for (int f = 0; f < 4; ++f) {
      af[f]  = *(const bf16x8*)&As[wm + f * 16 + fr][fk];
      bfr[f] = *(const bf16x8*)&Bs[wn + f * 16 + fr][fk];
    }
#pragma unroll
    for (int mf = 0; mf < 4; ++mf)
#pragma unroll
      for (int nf = 0; nf < 4; ++nf)
        acc[mf][nf] = __builtin_amdgcn_mfma_f32_16x16x32_bf16(
            af[mf], bfr[nf], acc[mf][nf], 0, 0, 0);
    __syncthreads();
  }

  float bv[4];
#pragma unroll
  for (int nf = 0; nf < 4; ++nf)
    bv[nf] = HASBIAS ? bias[bn + wn + nf * 16 + fr] : 0.f;

  const int crow0 = (lane >> 4) * 4;
#pragma unroll
  for (int mf = 0; mf < 4; ++mf)
#pragma unroll
    for (int r = 0; r < 4; ++r) {
      const long roff = (long)(bm + wm + mf * 16 + crow0 + r) * ldc + bn + wn;
#pragma unroll
      for (int nf = 0; nf < 4; ++nf) {
        float v = acc[mf][nf][r] + bv[nf];
        if (OUTBF) {
          unsigned u = __float_as_uint(v);
          u += 0x7fffu + ((u >> 16) & 1u);
          Cb[roff + nf * 16 + fr] = (ushort)(u >> 16);
        } else {
          if (ACCUM) v += Cf[roff + nf * 16 + fr];
          if (RELU) v = fmaxf(v, 0.f);
          Cf[roff + nf * 16 + fr] = v;
        }
      }
    }
}

// ---------------------------------------------------------------------------
// helpers
// ---------------------------------------------------------------------------
__device__ __forceinline__ unsigned short f2bf(float f) {
  unsigned u = __float_as_uint(f);
  u += 0x7fffu + ((u >> 16) & 1u);
  return (unsigned short)(u >> 16);
}
__device__ __forceinline__ float bf2f(ushort v) {
  return __uint_as_float(((unsigned)v) << 16);
}
__device__ __forceinline__ float fast_sig(float x) {
  return __builtin_amdgcn_rcpf(1.f + __expf(-x));
}
__device__ __forceinline__ float fast_tanh(float x) {
  return 2.f * fast_sig(2.f * x) - 1.f;
}

__device__ __forceinline__ int sdot4_(uint a, uint b, int c) {
#if __has_builtin(__builtin_amdgcn_sdot4)
  return __builtin_amdgcn_sdot4((int)a, (int)b, c, false);
#else
  int r = c;
  r += ((int)(a << 24) >> 24) * ((int)(b << 24) >> 24);
  r += ((int)(a << 16) >> 24) * ((int)(b << 16) >> 24);
  r += ((int)(a << 8)  >> 24) * ((int)(b << 8)  >> 24);
  r += ((int)a >> 24)         * ((int)b >> 24);
  return r;
#endif
}

// ---------------------------------------------------------------------------
// prep1: Whh int8 pack (bids 0..1023) + W_rel basis combination (1024..1535)
// ---------------------------------------------------------------------------
__global__ __launch_bounds__(256) void prep1_k(
    const float* __restrict__ Whh0, const float* __restrict__ Whh1,
    uint* __restrict__ Wq, float* __restrict__ fscale,
    const float* __restrict__ basis, const float* __restrict__ comp,
    ushort* __restrict__ wrel2t)
{
  __shared__ float cs[240];
  const int bid = blockIdx.x;
  if (bid < 1024) {
    const int wid = (bid * 256 + threadIdx.x) >> 6;
    const int lane = threadIdx.x & 63;
    const int l = wid >> 11;
    const int wid2 = wid & 2047;
    const int d = wid2 >> 10, gi = wid2 & 1023;
    const float* Whh = l ? Whh1 : Whh0;
    const float* row = Whh + ((long)d * 1024 + gi) * 256 + lane * 4;
    float v0 = row[0], v1 = row[1], v2 = row[2], v3 = row[3];
    float am = fmaxf(fmaxf(fabsf(v0), fabsf(v1)), fmaxf(fabsf(v2), fabsf(v3)));
#pragma unroll
    for (int off = 32; off > 0; off >>= 1) am = fmaxf(am, __shfl_xor(am, off, 64));
    am = fmaxf(am, 1e-12f);
    const float inv = 127.f / am;
    int q0 = __float2int_rn(v0 * inv), q1 = __float2int_rn(v1 * inv);
    int q2 = __float2int_rn(v2 * inv), q3 = __float2int_rn(v3 * inv);
    uint w = (uint)(q0 & 255) | ((uint)(q1 & 255) << 8) |
             ((uint)(q2 & 255) << 16) | ((uint)(q3 & 255) << 24);
    Wq[(long)l * 131072 + ((long)d * 64 + lane) * 1024 + gi] = w;
    if (lane == 0) fscale[l * 2048 + d * 1024 + gi] = am / 127.f;
    return;
  }
  const int f = bid - 1024;
  const int o = threadIdx.x;
  if (o < 240) cs[o] = comp[o];
  __syncthreads();
  float acc[8];
#pragma unroll
  for (int r = 0; r < 8; ++r) acc[r] = 0.f;
  for (int bb = 0; bb < 30; ++bb) {
    const float v = basis[((long)bb * 512 + f) * 256 + o];
#pragma unroll
    for (int r = 0; r < 8; ++r) acc[r] = fmaf(cs[r * 30 + bb], v, acc[r]);
  }
#pragma unroll
  for (int r = 0; r < 8; ++r)
    wrel2t[((long)(r * 256 + o)) * 512 + f] = f2bf(acc[r]);
}

// ---------------------------------------------------------------------------
// prep2: f32->bf16 cvt (U/Wih0/Wih1, bids 0..11263), stacked bias (11264/5),
// transpose jobs (11266..12353).
// ---------------------------------------------------------------------------
__global__ __launch_bounds__(256) void prep2_k(
    const float* __restrict__ U, ushort* __restrict__ ubf,
    const float* __restrict__ W0, ushort* __restrict__ w0,
    const float* __restrict__ W1, ushort* __restrict__ w1,
    const float* __restrict__ b_rgcn, float* __restrict__ biasSW,
    const float* __restrict__ s0, ushort* __restrict__ d0,   // W_root
    const float* __restrict__ s1, const float* __restrict__ s2,
    ushort* __restrict__ d12,                                // gc stacked
    const float* __restrict__ s3, ushort* __restrict__ d3,   // Wm
    const float* __restrict__ s4, ushort* __restrict__ d4,   // Wl
    const float* __restrict__ s5, ushort* __restrict__ d5)   // W_scalar
{
  __shared__ float tile[32][33];
  const int bid0 = blockIdx.x;
  if (bid0 < 11264) {
    const float* src; ushort* dst; long base;
    if (bid0 < 8192)       { src = U;  dst = ubf; base = (long)bid0 * 1024; }
    else if (bid0 < 10240) { src = W0; dst = w0;  base = (long)(bid0 - 8192) * 1024; }
    else                   { src = W1; dst = w1;  base = (long)(bid0 - 10240) * 1024; }
    const long i = base + threadIdx.x * 4;
    float4 v = *(const float4*)(src + i);
    ushort4 o;
    o.x = f2bf(v.x); o.y = f2bf(v.y); o.z = f2bf(v.z); o.w = f2bf(v.w);
    *(ushort4*)(dst + i) = o;
    return;
  }
  if (bid0 < 11266) {
    const int idx = (bid0 - 11264) * 256 + threadIdx.x;
    if (idx < 384) biasSW[idx] = (idx < 128) ? 0.f : b_rgcn[idx - 128];
    return;
  }
  const int bid = bid0 - 11266;  // 0..1087
  const float* src; ushort* dst; int C, gx, local, dstStride, dstOff;
  if (bid < 128)       { src = s0; dst = d0;  C = 256; gx = 8;  local = bid;        dstStride = 512; dstOff = 0; }
  else if (bid < 192)  { src = s1; dst = d12; C = 256; gx = 8;  local = bid - 128;  dstStride = 512; dstOff = 0; }
  else if (bid < 256)  { src = s2; dst = d12; C = 256; gx = 8;  local = bid - 192;  dstStride = 512; dstOff = 256; }
  else if (bid < 832)  { src = s3; dst = d3;  C = 768; gx = 24; local = bid - 256;  dstStride = 768; dstOff = 0; }
  else if (bid < 1024) { src = s4; dst = d4;  C = 256; gx = 8;  local = bid - 832;  dstStride = 768; dstOff = 0; }
  else                 { src = s5; dst = d5;  C = 128; gx = 4;  local = bid - 1024; dstStride = 512; dstOff = 0; }
  const int c0 = (local % gx) * 32, r0 = (local / gx) * 32;
  const int tx = threadIdx.x & 31, ty = threadIdx.x >> 5;
#pragma unroll
  for (int j = 0; j < 4; ++j)
    tile[ty + j * 8][tx] = src[(long)(r0 + ty + j * 8) * C + c0 + tx];
  __syncthreads();
#pragma unroll
  for (int j = 0; j < 4; ++j)
    dst[(long)(c0 + ty + j * 8) * dstStride + dstOff + r0 + tx] = f2bf(tile[tx][ty + j * 8]);
}

// ---------------------------------------------------------------------------
// LSTM v4 (proven; bf16 gates): int8 weights streamed from L2, int8 h via
// LDS broadcast, sdot4; bf16 output with row stride ldo.
// ---------------------------------------------------------------------------
__global__ __launch_bounds__(1024) void lstm4_k(
    const ushort* __restrict__ Xg,
    const uint* __restrict__ Wq,
    const float* __restrict__ fscale,
    ushort* __restrict__ out,
    int bmajor, long ldo)
{
  const int bx = blockIdx.x;
  const int d = bx >> 6, b = bx & 63;
  const int tid = threadIdx.x;

  __shared__ uint hq[2][64];
  __shared__ float preactF[1024];

  uint w[64];
  const uint* wrow = Wq + (long)d * 65536 + tid;
#pragma unroll
  for (int k4 = 0; k4 < 64; ++k4) w[k4] = wrow[k4 * 1024];

  if (tid < 128) ((uint*)hq)[tid] = 0u;

  const float fsc = fscale[d * 1024 + tid] * (1.0f / 127.0f);
  const ushort* Xd = Xg + (long)d * 8192 * 1024;

  float c = 0.f;
  float x0 = 0.f, x1 = 0.f, x2 = 0.f, x3 = 0.f;
  if (tid < 256) {
    const ushort* xr = Xd + ((long)((d ? 127 : 0) * 64 + b)) * 1024;
    x0 = bf2f(xr[tid]); x1 = bf2f(xr[tid + 256]);
    x2 = bf2f(xr[tid + 512]); x3 = bf2f(xr[tid + 768]);
  }
  __syncthreads();

  int cur = 0;
  for (int step = 0; step < 128; ++step) {
    const int t = d ? 127 - step : step;

    float n0 = 0.f, n1 = 0.f, n2 = 0.f, n3 = 0.f;
    if (tid < 256 && step + 1 < 128) {
      const ushort* xr = Xd + ((long)((d ? 126 - step : step + 1) * 64 + b)) * 1024;
      n0 = bf2f(xr[tid]); n1 = bf2f(xr[tid + 256]);
      n2 = bf2f(xr[tid + 512]); n3 = bf2f(xr[tid + 768]);
    }

    int acc = 0;
    const uint4* hrow = (const uint4*)hq[cur];
#pragma unroll
    for (int k16 = 0; k16 < 16; ++k16) {
      uint4 h4 = hrow[k16];
      acc = sdot4_(w[k16 * 4 + 0], h4.x, acc);
      acc = sdot4_(w[k16 * 4 + 1], h4.y, acc);
      acc = sdot4_(w[k16 * 4 + 2], h4.z, acc);
      acc = sdot4_(w[k16 * 4 + 3], h4.w, acc);
    }
    preactF[tid] = (float)acc * fsc;
    __syncthreads();

    if (tid < 256) {
      float p0 = x0 + preactF[tid];
      float p1 = x1 + preactF[tid + 256];
      float p2 = x2 + preactF[tid + 512];
      float p3 = x3 + preactF[tid + 768];
      const float ig = fast_sig(p0), fg = fast_sig(p1);
      const float gg = fast_tanh(p2), og = fast_sig(p3);
      c = fg * c + ig * gg;
      const float h = og * fast_tanh(c);
      const long row = bmajor ? ((long)b * 128 + t) : ((long)t * 64 + b);
      out[row * ldo + (d << 8) + tid] = f2bf(h);
      ((char*)hq[cur ^ 1])[tid] = (char)__float2int_rn(h * 127.f);
      x0 = n0; x1 = n1; x2 = n2; x3 = n3;
    }
    __syncthreads();
    cur ^= 1;
  }
}

// ---------------------------------------------------------------------------
// RGCN gather FUSED with edge-attention softmax (proven). scaleM [8192][384]:
// cols [0:128) = scale, cols [128:384) = hroot.
// ---------------------------------------------------------------------------
__global__ __launch_bounds__(256) void rgcn_fused_k(
    const float* __restrict__ scaleM, const ushort* __restrict__ xrel,
    const int* __restrict__ spk, ushort* __restrict__ hagg)
{
  const int n = blockIdx.x;
  const int b = n >> 7, t = n & 127;
  const int o = threadIdx.x;
  const int lo = max(t - 10, 0), hi = min(t + 10, 127);
  const int cnt = hi - lo + 1;

  __shared__ float sc[128], red[128];
  __shared__ int spks[21];
  __shared__ int spkt_s;

  if (o < 128) {
    const float v = scaleM[((long)(b * 128 + o)) * 384 + t];
    sc[o] = v; red[o] = v;
  }
  if (o == 0) spkt_s = spk[t * 64 + b];
  if (o >= 128 && o - 128 < cnt) spks[o - 128] = spk[(lo + o - 128) * 64 + b];
  __syncthreads();
  for (int off = 64; off > 0; off >>= 1) {
    if (o < off) red[o] = fmaxf(red[o], red[o + off]);
    __syncthreads();
  }
  const float m = red[0];
  __syncthreads();
  if (o < 128) {
    const float e = expf(sc[o] - m);
    sc[o] = e;
    const int dd = o - t;
    const bool inwin = (dd <= 10) && (dd >= -10);
    red[o] = e * (inwin ? 1.0f : 1e-10f);
  }
  __syncthreads();
  for (int off = 64; off > 0; off >>= 1) {
    if (o < off) red[o] += red[o + off];
    __syncthreads();
  }
  const float inv_msum = 1.0f / red[0];
  __syncthreads();

  const int spkt = spkt_s;
  float acc = scaleM[(long)n * 384 + 128 + o];
  for (int q = 0; q < cnt; ++q) {
    const int s = lo + q;
    const float wv = sc[s] * inv_msum;
    const int et = spkt * 4 + spks[q] * 2 + ((t < s) ? 0 : 1);
    acc = fmaf(bf2f(xrel[(((long)(b * 128 + s)) * 8 + et) * 256 + o]), wv, acc);
  }
  hagg[(long)n * 512 + o] = f2bf(acc);
}

// GraphConv neighbor aggregation: reads h half, writes agg half (cols 256+)
__global__ __launch_bounds__(256) void agg_k(ushort* __restrict__ hagg) {
  const int n = blockIdx.x;
  const int b = n >> 7, t = n & 127;
  const int o = threadIdx.x;
  const int lo = max(t - 10, 0), hi = min(t + 10, 127);
  float acc = 0.f;
  for (int s = lo; s <= hi; ++s) acc += bf2f(hagg[((long)(b * 128 + s)) * 512 + o]);
  hagg[(long)n * 512 + 256 + o] = f2bf(acc);
}

// Batched ushort transpose: dst[b](C x R) = src[b](R x C)^T, R=128, C=768.
__global__ __launch_bounds__(256) void emt_k(const ushort* __restrict__ src,
                                             ushort* __restrict__ dst) {
  __shared__ ushort tile[32][33];
  const int c0 = blockIdx.x * 32;
  const int r0 = blockIdx.y * 32;
  const int b = blockIdx.z;
  const ushort* s = src + (long)b * 98304;
  ushort* d = dst + (long)b * 98304;
  const int tx = threadIdx.x & 31, ty = threadIdx.x >> 5;
#pragma unroll
  for (int j = 0; j < 4; ++j)
    tile[ty + j * 8][tx] = s[(long)(r0 + ty + j * 8) * 768 + c0 + tx];
  __syncthreads();
#pragma unroll
  for (int j = 0; j < 4; ++j)
    d[(long)(c0 + ty + j * 8) * 128 + r0 + tx] = tile[tx][ty + j * 8];
}

// Matching attention probs: logits f32 in, bf16 a out
__global__ __launch_bounds__(128) void match_softmax_k(const float* __restrict__ logits,
                                                       const float* __restrict__ umask,
                                                       ushort* __restrict__ abf) {
  const int bx = blockIdx.x;           // b*128 + t
  const int b = bx >> 7;
  const int s = threadIdx.x;
  __shared__ float red[128];
  const float* row = logits + (long)bx * 128;
  const float um = umask[b * 128 + s];
  const float v = tanhf(row[s] * um * um);
  red[s] = v; __syncthreads();
  for (int off = 64; off > 0; off >>= 1) { if (s < off) red[s] = fmaxf(red[s], red[s + off]); __syncthreads(); }
  const float m = red[0]; __syncthreads();
  const float e = expf(v - m);
  red[s] = e; __syncthreads();
  for (int off = 64; off > 0; off >>= 1) { if (s < off) red[s] += red[s + off]; __syncthreads(); }
  const float es = red[0]; __syncthreads();
  const float p = (e / es) * um;
  red[s] = p; __syncthreads();
  for (int off = 64; off > 0; off >>= 1) { if (s < off) red[s] += red[s + off]; __syncthreads(); }
  const float ps = red[0];
  abf[(long)bx * 128 + s] = f2bf(p / ps);
}

__global__ __launch_bounds__(256) void final_k(const float* __restrict__ hidden,
                                               const float* __restrict__ Ws,
                                               const float* __restrict__ bs,
                                               float* __restrict__ out) {
  __shared__ float wsl[256 * 6];
  const int tid = threadIdx.x;
#pragma unroll
  for (int j = 0; j < 6; ++j) wsl[tid * 6 + j] = Ws[tid * 6 + j];
  __syncthreads();
  const int wave = tid >> 6, lane = tid & 63;
  const int n = blockIdx.x * 4 + wave;
  const float4 hv = *(const float4*)&hidden[(long)n * 256 + lane * 4];
  const float hvv[4] = {hv.x, hv.y, hv.z, hv.w};
  float a[6];
#pragma unroll
  for (int c = 0; c < 6; ++c) a[c] = 0.f;
#pragma unroll
  for (int j = 0; j < 4; ++j)
#pragma unroll
    for (int c = 0; c < 6; ++c)
      a[c] = fmaf(hvv[j], wsl[(lane * 4 + j) * 6 + c], a[c]);
#pragma unroll
  for (int off = 32; off > 0; off >>= 1)
#pragma unroll
    for (int c = 0; c < 6; ++c)
      a[c] += __shfl_xor(a[c], off, 64);
  if (lane == 0) {
    float v[6], m = -1e30f;
#pragma unroll
    for (int c = 0; c < 6; ++c) { v[c] = a[c] + bs[c]; m = fmaxf(m, v[c]); }
    float sum = 0.f;
#pragma unroll
    for (int c = 0; c < 6; ++c) sum += expf(v[c] - m);
    const float lse = m + logf(sum);
#pragma unroll
    for (int c = 0; c < 6; ++c) out[(long)n * 6 + c] = v[c] - lse;
  }
}

// ---------------------------------------------------------------------------
// Orchestration
// ---------------------------------------------------------------------------
extern "C" void kernel_launch(void* const* d_in, const int* in_sizes, int n_in,
                              void* d_out, int out_size, void* d_ws, size_t ws_size,
                              hipStream_t stream) {
  const float* U        = (const float*)d_in[0];
  const float* umask    = (const float*)d_in[1];
  const float* Wih0     = (const float*)d_in[2];
  const float* Whh0     = (const float*)d_in[3];
  const float* b0       = (const float*)d_in[4];
  const float* Wih1     = (const float*)d_in[5];
  const float* Whh1     = (const float*)d_in[6];
  const float* b1       = (const float*)d_in[7];
  const float* W_scalar = (const float*)d_in[8];
  const float* basis    = (const float*)d_in[9];
  const float* comp     = (const float*)d_in[10];
  const float* W_root   = (const float*)d_in[11];
  const float* b_rgcn   = (const float*)d_in[12];
  const float* gc_W1    = (const float*)d_in[13];
  const float* gc_W2    = (const float*)d_in[14];
  const float* gc_b     = (const float*)d_in[15];
  const float* Wm       = (const float*)d_in[16];
  const float* bm       = (const float*)d_in[17];
  const float* Wl       = (const float*)d_in[18];
  const float* bl       = (const float*)d_in[19];
  const float* Wsw      = (const float*)d_in[20];
  const float* bsw      = (const float*)d_in[21];
  const int*   speakers = (const int*)d_in[22];

  float* ws = (float*)d_ws;
  float* gates   = ws + 0L;          // 16.78M f: gatesbf | scaleM -> xrelbf -> xtrbf
  float* feats   = ws + 16777216L;   //  4.19M f: wih0bf/wih1bf -> attbf
  float* xbuf    = ws + 20971520L;   //  4.19M f: ubf -> hagg -> emT
  float* feats0  = ws + 25165824L;   //  4.19M f: f0bf -> xemb [8192][768]
  float* scaleb  = ws + 29360128L;   //  1.05M f: logits -> hidden(lo)
  float* scoresb = ws + 30408704L;   //  1.05M f: abf -> hidden(hi)
  float* wrelr   = ws + 31457280L;   //  1.05M f: wrel2t bf16
  uint*  wq      = (uint*)(ws + 34603008L);   // 262,144 dwords
  float* fsc     = ws + 34865152L;            // 4,096
  float* wTr     = ws + 34869248L;            // 557,056 f (transposed weights)
  float* biasSW  = ws + 35426304L;            // 384 f

  ushort* ubf    = (ushort*)xbuf;
  ushort* wih0bf = (ushort*)feats;
  ushort* wih1bf = (ushort*)(feats + 1048576L);
  ushort* f0bf   = (ushort*)feats0;
  ushort* xemb   = (ushort*)feats0;              // [8192][768]
  ushort* wrel2t = (ushort*)wrelr;
  ushort* wswr   = (ushort*)wTr;                 // 384x512 stacked
  ushort* gcW12t = wswr + 196608L;               // 256x512 stacked
  ushort* Wmt    = gcW12t + 131072L;             // 768x768
  ushort* Wlt    = Wmt + 589824L;                // 256x768

  ushort* gatesbf = (ushort*)gates;
  float*  scaleM  = gates + 8388608L;            // [8192][384]
  ushort* hagg    = (ushort*)xbuf;               // [8192][512]
  ushort* emT     = (ushort*)xbuf;               // [64][768][128]
  ushort* xrelbf  = (ushort*)gates;
  ushort* xtrbf   = (ushort*)gates;
  ushort* abf     = (ushort*)scoresb;
  ushort* attbf   = (ushort*)feats;

  float*  logitsb = scaleb;
  float*  hiddenb = scaleb;

  // --- weight prep (2 dispatches) ---
  prep1_k<<<1536, 256, 0, stream>>>(Whh0, Whh1, wq, fsc, basis, comp, wrel2t);
  prep2_k<<<12354, 256, 0, stream>>>(U, ubf, Wih0, wih0bf, Wih1, wih1bf,
                                     b_rgcn, biasSW,
                                     W_root, wswr + 65536L, gc_W1, gc_W2, gcW12t,
                                     Wm, Wmt, Wl, Wlt, W_scalar, wswr);

  // --- layer 0 ---
  gemm_bf16_nt<true, false, false, true><<<dim3(8, 64, 2), 256, 0, stream>>>(
      ubf, wih0bf, b0, gatesbf, 8192, 1024, 1024, 1024L, 1024L,
      0L, 1048576L, 8388608L, 1024L);
  lstm4_k<<<128, 1024, 0, stream>>>(gatesbf, wq, fsc, f0bf, 0, 512L);

  // --- layer 1 ---
  gemm_bf16_nt<true, false, false, true><<<dim3(8, 64, 2), 256, 0, stream>>>(
      f0bf, wih1bf, b1, gatesbf, 8192, 1024, 512, 512L, 1024L,
      0L, 524288L, 8388608L, 1024L);
  lstm4_k<<<128, 1024, 0, stream>>>(gatesbf, wq + 131072, fsc + 2048, xemb, 1, 768L);

  // --- merged edge-scale | W_root GEMM + xrel + fused RGCN ---
  gemm_bf16_nt<true, false, false, false><<<dim3(3, 64, 1), 256, 0, stream>>>(
      xemb, wswr, biasSW, scaleM, 8192, 384, 512, 768L, 384L, 0L, 0L, 0L, 0L);
  gemm_bf16_nt<false, false, false, true><<<dim3(16, 64, 1), 256, 0, stream>>>(
      xemb, wrel2t, nullptr, xrelbf, 8192, 2048, 512, 768L, 2048L, 0L, 0L, 0L, 0L);
  rgcn_fused_k<<<8192, 256, 0, stream>>>(scaleM, xrelbf, speakers, hagg);

  // --- GraphConv ---
  agg_k<<<8192, 256, 0, stream>>>(hagg);
  gemm_bf16_nt<true, false, false, true><<<dim3(2, 64, 1), 256, 0, stream>>>(
      hagg, gcW12t, gc_b, xemb + 512, 8192, 256, 512, 512L, 768L, 0L, 0L, 0L, 0L);

  // --- matching attention (proven r16 structure) ---
  gemm_bf16_nt<true, false, false, true><<<dim3(6, 64, 1), 256, 0, stream>>>(
      xemb, Wmt, bm, xtrbf, 8192, 768, 768, 768L, 768L, 0L, 0L, 0L, 0L);
  emt_k<<<dim3(24, 4, 64), 256, 0, stream>>>(xemb, emT);
  gemm_bf16_nt<false, false, false, false><<<dim3(1, 1, 64), 256, 0, stream>>>(
      xtrbf, xemb, nullptr, logitsb, 128, 128, 768, 768L, 128L,
      98304L, 98304L, 16384L, 0L);
  match_softmax_k<<<8192, 128, 0, stream>>>(logitsb, umask, abf);
  gemm_bf16_nt<false, false, false, true><<<dim3(6, 1, 64), 256, 0, stream>>>(
      abf, emT, nullptr, attbf, 128, 768, 128, 128L, 768L,
      16384L, 98304L, 98304L, 0L);

  // --- classifier ---
  gemm_bf16_nt<true, false, true, false><<<dim3(2, 64, 1), 256, 0, stream>>>(
      attbf, Wlt, bl, hiddenb, 8192, 256, 768, 768L, 256L, 0L, 0L, 0L, 0L);
  final_k<<<2048, 256, 0, stream>>>(hiddenb, Wsw, bsw, (float*)d_out);
}